// Round 1
// baseline (553.336 us; speedup 1.0000x reference)
//
#include <hip/hip_runtime.h>
#include <math.h>

#define HIDc 64
#define HEADSc 4
#define HCc 256   // HEADS*HID

// ---------------- K1: h = x @ W_gat  (+ a_src, a_dst) ----------------
// block = 256 threads, 32 nodes/block. Thread t owns output column t (head=t>>6, c=t&63).
__global__ __launch_bounds__(256) void k1_gemm1(
    const float* __restrict__ x, const float* __restrict__ Wg,
    const float* __restrict__ att_src, const float* __restrict__ att_dst,
    float* __restrict__ h, float* __restrict__ a_src, float* __restrict__ a_dst,
    int N)
{
    __shared__ float xs[32][HIDc];          // 8 KB
    const int t = threadIdx.x;
    const int base = blockIdx.x * 32;
    for (int i = t; i < 32 * HIDc; i += 256) {
        int n = i >> 6, k = i & 63;
        int gn = base + n;
        xs[n][k] = (gn < N) ? x[(size_t)gn * HIDc + k] : 0.f;
    }
    __syncthreads();

    float acc[32];
#pragma unroll
    for (int n = 0; n < 32; ++n) acc[n] = 0.f;
    for (int k = 0; k < HIDc; ++k) {
        float w = Wg[k * HCc + t];          // coalesced 1KB/iter, read once per block
#pragma unroll
        for (int n = 0; n < 32; ++n) acc[n] += xs[n][k] * w;   // xs broadcast
    }

    const int head = t >> 6, c = t & 63;
    const float asv = att_src[t];           // att_src[H][HID] flat index == t
    const float adv = att_dst[t];

    for (int n = 0; n < 32; ++n) {
        int gn = base + n;
        if (gn < N) h[(size_t)gn * HCc + t] = acc[n];
    }
    // per-wave (== per-head) reduction for a_src/a_dst
    for (int n = 0; n < 32; ++n) {
        float ps = acc[n] * asv;
        float pd = acc[n] * adv;
#pragma unroll
        for (int off = 32; off > 0; off >>= 1) {
            ps += __shfl_down(ps, off, 64);
            pd += __shfl_down(pd, off, 64);
        }
        if (c == 0) {
            int gn = base + n;
            if (gn < N) {
                a_src[gn * HEADSc + head] = ps;
                a_dst[gn * HEADSc + head] = pd;
            }
        }
    }
}

// ---------------- K2a: count in-degrees (incl. self-loops) ----------------
__global__ void k2_count(const int* __restrict__ ei, int* __restrict__ counts,
                         int E, int N)
{
    int i = blockIdx.x * blockDim.x + threadIdx.x;
    int total = E + N;
    if (i < total) {
        int d = (i < E) ? ei[E + i] : (i - E);   // row1 = dst
        atomicAdd(&counts[d], 1);
    }
}

// ---------------- K2b: exclusive scan (single block, wave-hierarchical) ----
__global__ __launch_bounds__(1024) void k2_scan(
    const int* __restrict__ counts, int* __restrict__ offsets,
    int* __restrict__ cursor, int N)
{
    __shared__ int wsum[16];
    __shared__ int carry_s;
    const int t = threadIdx.x;
    const int lane = t & 63, wid = t >> 6;
    if (t == 0) carry_s = 0;
    __syncthreads();
    for (int base = 0; base < N; base += 1024) {
        int i = base + t;
        int v = (i < N) ? counts[i] : 0;
        int incl = v;
#pragma unroll
        for (int off = 1; off < 64; off <<= 1) {
            int u = __shfl_up(incl, off, 64);
            if (lane >= off) incl += u;
        }
        if (lane == 63) wsum[wid] = incl;
        __syncthreads();
        if (wid == 0 && lane < 16) {
            int winc = wsum[lane];
#pragma unroll
            for (int off = 1; off < 16; off <<= 1) {
                int u = __shfl_up(winc, off, 64);
                if (lane >= off) winc += u;
            }
            wsum[lane] = winc;
        }
        __syncthreads();
        int woff = (wid > 0) ? wsum[wid - 1] : 0;
        int carry = carry_s;
        int excl = carry + woff + incl - v;
        if (i < N) { offsets[i] = excl; cursor[i] = excl; }
        __syncthreads();
        if (t == 0) carry_s += wsum[15];
        __syncthreads();
    }
    if (t == 0) offsets[N] = carry_s;
}

// ---------------- K2c: fill CSR (store src per slot, grouped by dst) -------
__global__ void k2_fill(const int* __restrict__ ei, int* __restrict__ cursor,
                        int* __restrict__ csr_src, int E, int N)
{
    int i = blockIdx.x * blockDim.x + threadIdx.x;
    int total = E + N;
    if (i < total) {
        int s, d;
        if (i < E) { s = ei[i]; d = ei[E + i]; }
        else       { s = d = i - E; }
        int pos = atomicAdd(&cursor[d], 1);
        csr_src[pos] = s;
    }
}

// ---------------- K3: per-dst online-softmax aggregation + bias + ELU ------
// block = 256 = 4 waves; wave == head; lane == channel c. One block per node.
__global__ __launch_bounds__(256) void k3_aggregate(
    const float* __restrict__ h, const float* __restrict__ a_src,
    const float* __restrict__ a_dst, const int* __restrict__ offsets,
    const int* __restrict__ csr_src, const float* __restrict__ bias,
    float* __restrict__ act, int N)
{
    const int n = blockIdx.x;
    const int head = threadIdx.x >> 6, c = threadIdx.x & 63;
    const int beg = offsets[n], end = offsets[n + 1];
    const float adst = a_dst[n * HEADSc + head];

    float m = -1e30f, s = 0.f, acc = 0.f;
    for (int e = beg; e < end; ++e) {
        int sn = csr_src[e];
        float alpha = a_src[sn * HEADSc + head] + adst;   // broadcast load
        alpha = (alpha > 0.f) ? alpha : 0.2f * alpha;     // leaky_relu
        float hv = h[(size_t)sn * HCc + head * HIDc + c]; // coalesced 256B/wave
        if (alpha > m) {                                  // wave-uniform branch
            float sc = __expf(m - alpha);                 // first iter: exp(-inf)=0
            s = s * sc + 1.f;
            acc = acc * sc + hv;
            m = alpha;
        } else {
            float p = __expf(alpha - m);
            s += p;
            acc += p * hv;
        }
    }
    float o = acc / (s + 1e-16f);
    o += bias[threadIdx.x];
    o = (o > 0.f) ? o : (__expf(o) - 1.f);                // ELU
    act[(size_t)n * HCc + threadIdx.x] = o;
}

// ---------------- K4: out = act @ W_lin + b_lin ----------------------------
// block = 256, 16 nodes/block. Wave w owns nodes 4w..4w+3; lane j = out column.
__global__ __launch_bounds__(256) void k4_gemm2(
    const float* __restrict__ act, const float* __restrict__ Wl,
    const float* __restrict__ bl, float* __restrict__ out, int N)
{
    __shared__ float as[16][HCc];           // 16 KB
    const int t = threadIdx.x;
    const int base = blockIdx.x * 16;
    for (int i = t; i < 16 * HCc; i += 256) {
        int n = i >> 8, k = i & 255;
        as[n][k] = (base + n < N) ? act[(size_t)(base + n) * HCc + k] : 0.f;
    }
    __syncthreads();

    const int j = t & 63, ng = t >> 6;
    float acc[4] = {0.f, 0.f, 0.f, 0.f};
    for (int k = 0; k < HCc; ++k) {
        float w = Wl[k * HIDc + j];         // coalesced; reused over 4 nodes
#pragma unroll
        for (int i = 0; i < 4; ++i) acc[i] += as[ng * 4 + i][k] * w;
    }
    float b = bl[j];
#pragma unroll
    for (int i = 0; i < 4; ++i) {
        int gn = base + ng * 4 + i;
        if (gn < N) out[(size_t)gn * HIDc + j] = acc[i] + b;
    }
}

// ---------------------------------------------------------------------------
extern "C" void kernel_launch(void* const* d_in, const int* in_sizes, int n_in,
                              void* d_out, int out_size, void* d_ws, size_t ws_size,
                              hipStream_t stream)
{
    const float* x       = (const float*)d_in[0];
    const int*   ei      = (const int*)  d_in[1];
    const float* Wg      = (const float*)d_in[2];
    const float* att_src = (const float*)d_in[3];
    const float* att_dst = (const float*)d_in[4];
    const float* bias_g  = (const float*)d_in[5];
    const float* Wl      = (const float*)d_in[6];
    const float* bl      = (const float*)d_in[7];
    float* out = (float*)d_out;

    const int N = in_sizes[0] / HIDc;       // 50000
    const int E = in_sizes[1] / 2;          // 800000
    const int total = E + N;                // with self-loops

    // workspace carve-up (256B aligned)
    char* w = (char*)d_ws;
    size_t off = 0;
    auto carve = [&](size_t bytes) {
        void* p = w + off;
        off = (off + bytes + 255) & ~(size_t)255;
        return p;
    };
    float* h       = (float*)carve((size_t)N * HCc * 4);
    float* act     = (float*)carve((size_t)N * HCc * 4);
    float* a_src   = (float*)carve((size_t)N * HEADSc * 4);
    float* a_dst   = (float*)carve((size_t)N * HEADSc * 4);
    int*   counts  = (int*)  carve((size_t)N * 4);
    int*   offsets = (int*)  carve((size_t)(N + 1) * 4);
    int*   cursor  = (int*)  carve((size_t)N * 4);
    int*   csr_src = (int*)  carve((size_t)total * 4);
    (void)ws_size;

    hipMemsetAsync(counts, 0, (size_t)N * 4, stream);

    k1_gemm1<<<(N + 31) / 32, 256, 0, stream>>>(x, Wg, att_src, att_dst,
                                                h, a_src, a_dst, N);
    k2_count<<<(total + 255) / 256, 256, 0, stream>>>(ei, counts, E, N);
    k2_scan<<<1, 1024, 0, stream>>>(counts, offsets, cursor, N);
    k2_fill<<<(total + 255) / 256, 256, 0, stream>>>(ei, cursor, csr_src, E, N);
    k3_aggregate<<<N, 256, 0, stream>>>(h, a_src, a_dst, offsets, csr_src,
                                        bias_g, act, N);
    k4_gemm2<<<(N + 15) / 16, 256, 0, stream>>>(act, Wl, bl, out, N);
}

// Round 2
// 537.693 us; speedup vs baseline: 1.0291x; 1.0291x over previous
//
#include <hip/hip_runtime.h>
#include <math.h>

#define HIDc 64
#define HEADSc 4
#define HCc 256   // HEADS*HID

// ---------------- K1: h = x @ W_gat  (+ a_src, a_dst) ----------------
// block = 256 threads, 32 nodes/block. Thread t owns output column t (head=t>>6, c=t&63).
__global__ __launch_bounds__(256) void k1_gemm1(
    const float* __restrict__ x, const float* __restrict__ Wg,
    const float* __restrict__ att_src, const float* __restrict__ att_dst,
    float* __restrict__ h, float* __restrict__ a_src, float* __restrict__ a_dst,
    int N)
{
    __shared__ float xs[32][HIDc];          // 8 KB
    const int t = threadIdx.x;
    const int base = blockIdx.x * 32;
    for (int i = t; i < 32 * HIDc; i += 256) {
        int n = i >> 6, k = i & 63;
        int gn = base + n;
        xs[n][k] = (gn < N) ? x[(size_t)gn * HIDc + k] : 0.f;
    }
    __syncthreads();

    float acc[32];
#pragma unroll
    for (int n = 0; n < 32; ++n) acc[n] = 0.f;
    for (int k = 0; k < HIDc; ++k) {
        float w = Wg[k * HCc + t];          // coalesced 1KB/iter, read once per block
#pragma unroll
        for (int n = 0; n < 32; ++n) acc[n] += xs[n][k] * w;   // xs broadcast
    }

    const int head = t >> 6, c = t & 63;
    const float asv = att_src[t];           // att_src[H][HID] flat index == t
    const float adv = att_dst[t];

    for (int n = 0; n < 32; ++n) {
        int gn = base + n;
        if (gn < N) h[(size_t)gn * HCc + t] = acc[n];
    }
    // per-wave (== per-head) reduction for a_src/a_dst
    for (int n = 0; n < 32; ++n) {
        float ps = acc[n] * asv;
        float pd = acc[n] * adv;
#pragma unroll
        for (int off = 32; off > 0; off >>= 1) {
            ps += __shfl_down(ps, off, 64);
            pd += __shfl_down(pd, off, 64);
        }
        if (c == 0) {
            int gn = base + n;
            if (gn < N) {
                a_src[gn * HEADSc + head] = ps;
                a_dst[gn * HEADSc + head] = pd;
            }
        }
    }
}

// ---------------- K2a: count in-degrees (incl. self-loops) ----------------
__global__ void k2_count(const int* __restrict__ ei, int* __restrict__ counts,
                         int E, int N)
{
    int i = blockIdx.x * blockDim.x + threadIdx.x;
    int total = E + N;
    if (i < total) {
        int d = (i < E) ? ei[E + i] : (i - E);   // row1 = dst
        atomicAdd(&counts[d], 1);
    }
}

// ---------------- K2b: exclusive scan (single block, one pass) -------------
__global__ __launch_bounds__(1024) void k2_scan(
    const int* __restrict__ counts, int* __restrict__ offsets,
    int* __restrict__ cursor, int N)
{
    const int T = 1024;
    const int t = threadIdx.x;
    const int P = (N + T - 1) / T;          // elements per thread (49 for N=50000)
    const int lo = t * P;
    const int hi = min(lo + P, N);

    int sum = 0;
    for (int i = lo; i < hi; ++i) sum += counts[i];

    // block-wide exclusive scan of per-thread sums
    const int lane = t & 63, wid = t >> 6;
    __shared__ int wtot[16];
    int incl = sum;
#pragma unroll
    for (int o = 1; o < 64; o <<= 1) {
        int u = __shfl_up(incl, o, 64);
        if (lane >= o) incl += u;
    }
    if (lane == 63) wtot[wid] = incl;
    __syncthreads();
    if (t < 16) {
        int v = wtot[t];
        int inc2 = v;
#pragma unroll
        for (int o = 1; o < 16; o <<= 1) {
            int u = __shfl_up(inc2, o, 64);
            if (t >= o) inc2 += u;
        }
        wtot[t] = inc2;
    }
    __syncthreads();
    int excl = incl - sum + (wid ? wtot[wid - 1] : 0);

    int run = excl;
    for (int i = lo; i < hi; ++i) {
        offsets[i] = run;
        cursor[i]  = run;
        run += counts[i];
    }
    if (t == T - 1) offsets[N] = run;       // last thread's run == grand total
}

// ---------------- K2c: fill CSR (store src per slot, grouped by dst) -------
__global__ void k2_fill(const int* __restrict__ ei, int* __restrict__ cursor,
                        int* __restrict__ csr_src, int E, int N)
{
    int i = blockIdx.x * blockDim.x + threadIdx.x;
    int total = E + N;
    if (i < total) {
        int s, d;
        if (i < E) { s = ei[i]; d = ei[E + i]; }
        else       { s = d = i - E; }
        int pos = atomicAdd(&cursor[d], 1);
        csr_src[pos] = s;
    }
}

// ---------------- K3: per-dst softmax aggregation, two-phase, barrier-free -
// block = 256 = 4 waves; wave == head. One block per node. No __syncthreads:
// each wave owns its private LDS slab [head][*].
__global__ __launch_bounds__(256) void k3_aggregate(
    const float* __restrict__ h, const float* __restrict__ a_src,
    const float* __restrict__ a_dst, const int* __restrict__ offsets,
    const int* __restrict__ csr_src, const float* __restrict__ bias,
    float* __restrict__ act, int N)
{
    __shared__ float s_p[HEADSc][64];
    __shared__ int   s_src[HEADSc][64];

    const int n = blockIdx.x;
    const int head = threadIdx.x >> 6, lane = threadIdx.x & 63;
    const int beg = offsets[n], end = offsets[n + 1];
    const float adst = a_dst[n * HEADSc + head];

    float m = -1e30f, ssum = 0.f, acc = 0.f;

    for (int cb = beg; cb < end; cb += 64) {
        const int cnt = min(64, end - cb);

        // ---- phase 1: lane == edge slot (parallel alpha) ----
        const bool valid = lane < cnt;
        const int  sn = valid ? csr_src[cb + lane] : 0;
        float av = a_src[sn * HEADSc + head] + adst;
        av = (av > 0.f) ? av : 0.2f * av;                 // leaky_relu
        const float al = valid ? av : -1e30f;

        float mc = al;                                     // wave max
#pragma unroll
        for (int o = 1; o < 64; o <<= 1)
            mc = fmaxf(mc, __shfl_xor(mc, o, 64));

        const float p = __expf(al - mc);                   // invalid -> ~0
        float sc = p;                                      // wave sum
#pragma unroll
        for (int o = 1; o < 64; o <<= 1)
            sc += __shfl_xor(sc, o, 64);

        s_p[head][lane]   = p;
        s_src[head][lane] = sn;

        const float mnew      = fmaxf(m, mc);
        const float scale_old = __expf(m - mnew);          // 0 on first chunk
        const float f         = __expf(mc - mnew);

        // ---- phase 2: lane == channel c (gather + weighted accumulate) ----
        float accc = 0.f;
#pragma unroll 4
        for (int e = 0; e < cnt; ++e) {
            const float pe = s_p[head][e];                 // LDS broadcast
            const int   sv = s_src[head][e];
            accc += pe * h[(size_t)sv * HCc + head * HIDc + lane];
        }
        acc  = acc  * scale_old + accc * f;
        ssum = ssum * scale_old + sc   * f;
        m = mnew;
    }

    float o = acc / (ssum + 1e-16f);
    o += bias[threadIdx.x];
    o = (o > 0.f) ? o : (__expf(o) - 1.f);                 // ELU
    act[(size_t)n * HCc + threadIdx.x] = o;
}

// ---------------- K4: out = act @ W_lin + b_lin ----------------------------
// block = 256, 16 nodes/block. Wave w owns nodes 4w..4w+3; lane j = out column.
__global__ __launch_bounds__(256) void k4_gemm2(
    const float* __restrict__ act, const float* __restrict__ Wl,
    const float* __restrict__ bl, float* __restrict__ out, int N)
{
    __shared__ float as[16][HCc];           // 16 KB
    const int t = threadIdx.x;
    const int base = blockIdx.x * 16;
    for (int i = t; i < 16 * HCc; i += 256) {
        int n = i >> 8, k = i & 255;
        as[n][k] = (base + n < N) ? act[(size_t)(base + n) * HCc + k] : 0.f;
    }
    __syncthreads();

    const int j = t & 63, ng = t >> 6;
    float acc[4] = {0.f, 0.f, 0.f, 0.f};
    for (int k = 0; k < HCc; ++k) {
        float w = Wl[k * HIDc + j];         // coalesced; reused over 4 nodes
#pragma unroll
        for (int i = 0; i < 4; ++i) acc[i] += as[ng * 4 + i][k] * w;
    }
    float b = bl[j];
#pragma unroll
    for (int i = 0; i < 4; ++i) {
        int gn = base + ng * 4 + i;
        if (gn < N) out[(size_t)gn * HIDc + j] = acc[i] + b;
    }
}

// ---------------------------------------------------------------------------
extern "C" void kernel_launch(void* const* d_in, const int* in_sizes, int n_in,
                              void* d_out, int out_size, void* d_ws, size_t ws_size,
                              hipStream_t stream)
{
    const float* x       = (const float*)d_in[0];
    const int*   ei      = (const int*)  d_in[1];
    const float* Wg      = (const float*)d_in[2];
    const float* att_src = (const float*)d_in[3];
    const float* att_dst = (const float*)d_in[4];
    const float* bias_g  = (const float*)d_in[5];
    const float* Wl      = (const float*)d_in[6];
    const float* bl      = (const float*)d_in[7];
    float* out = (float*)d_out;

    const int N = in_sizes[0] / HIDc;       // 50000
    const int E = in_sizes[1] / 2;          // 800000
    const int total = E + N;                // with self-loops

    // workspace carve-up (256B aligned)
    char* w = (char*)d_ws;
    size_t off = 0;
    auto carve = [&](size_t bytes) {
        void* p = w + off;
        off = (off + bytes + 255) & ~(size_t)255;
        return p;
    };
    float* h       = (float*)carve((size_t)N * HCc * 4);
    float* act     = (float*)carve((size_t)N * HCc * 4);
    float* a_src   = (float*)carve((size_t)N * HEADSc * 4);
    float* a_dst   = (float*)carve((size_t)N * HEADSc * 4);
    int*   counts  = (int*)  carve((size_t)N * 4);
    int*   offsets = (int*)  carve((size_t)(N + 1) * 4);
    int*   cursor  = (int*)  carve((size_t)N * 4);
    int*   csr_src = (int*)  carve((size_t)total * 4);
    (void)ws_size;

    hipMemsetAsync(counts, 0, (size_t)N * 4, stream);

    k1_gemm1<<<(N + 31) / 32, 256, 0, stream>>>(x, Wg, att_src, att_dst,
                                                h, a_src, a_dst, N);
    k2_count<<<(total + 255) / 256, 256, 0, stream>>>(ei, counts, E, N);
    k2_scan<<<1, 1024, 0, stream>>>(counts, offsets, cursor, N);
    k2_fill<<<(total + 255) / 256, 256, 0, stream>>>(ei, cursor, csr_src, E, N);
    k3_aggregate<<<N, 256, 0, stream>>>(h, a_src, a_dst, offsets, csr_src,
                                        bias_g, act, N);
    k4_gemm2<<<(N + 15) / 16, 256, 0, stream>>>(act, Wl, bl, out, N);
}

// Round 3
// 402.757 us; speedup vs baseline: 1.3739x; 1.3350x over previous
//
#include <hip/hip_runtime.h>

#define HIDc 64
#define HEADSc 4
#define HCc 256   // HEADS*HID

typedef unsigned short ushort_t;
typedef unsigned int uint_t;

__device__ inline float bf2f(uint_t lo16) { return __uint_as_float(lo16 << 16); }
__device__ inline ushort_t f2bf(float f) {  // RNE
    uint_t u = __float_as_uint(f);
    u += 0x7FFFu + ((u >> 16) & 1u);
    return (ushort_t)(u >> 16);
}

// ---------------- K1: h = x @ W_gat  (+ a_src, a_dst); h stored bf16 -------
__global__ __launch_bounds__(256) void k1_gemm1(
    const float* __restrict__ x, const float* __restrict__ Wg,
    const float* __restrict__ att_src, const float* __restrict__ att_dst,
    ushort_t* __restrict__ h, float* __restrict__ a_src, float* __restrict__ a_dst,
    int N)
{
    __shared__ float xs[32][HIDc];          // 8 KB
    const int t = threadIdx.x;
    const int base = blockIdx.x * 32;
    for (int i = t; i < 32 * HIDc; i += 256) {
        int n = i >> 6, k = i & 63;
        int gn = base + n;
        xs[n][k] = (gn < N) ? x[(size_t)gn * HIDc + k] : 0.f;
    }
    __syncthreads();

    float acc[32];
#pragma unroll
    for (int n = 0; n < 32; ++n) acc[n] = 0.f;
    for (int k = 0; k < HIDc; ++k) {
        float w = Wg[k * HCc + t];          // Wg is 64KB total -> L2-resident
#pragma unroll
        for (int n = 0; n < 32; ++n) acc[n] += xs[n][k] * w;
    }

    const int head = t >> 6, c = t & 63;
    const float asv = att_src[t];
    const float adv = att_dst[t];

    for (int n = 0; n < 32; ++n) {
        int gn = base + n;
        if (gn < N) h[(size_t)gn * HCc + t] = f2bf(acc[n]);
    }
    for (int n = 0; n < 32; ++n) {
        float ps = acc[n] * asv;
        float pd = acc[n] * adv;
#pragma unroll
        for (int off = 32; off > 0; off >>= 1) {
            ps += __shfl_down(ps, off, 64);
            pd += __shfl_down(pd, off, 64);
        }
        if (c == 0) {
            int gn = base + n;
            if (gn < N) {
                a_src[gn * HEADSc + head] = ps;
                a_dst[gn * HEADSc + head] = pd;
            }
        }
    }
}

// ---------------- K2a: count in-degrees (incl. self-loops) ----------------
__global__ void k2_count(const int* __restrict__ ei, int* __restrict__ counts,
                         int E, int N)
{
    int i = blockIdx.x * blockDim.x + threadIdx.x;
    int total = E + N;
    if (i < total) {
        int d = (i < E) ? ei[E + i] : (i - E);
        atomicAdd(&counts[d], 1);
    }
}

// ---------------- K2b: parallel scan, 3 kernels ----------------------------
// scanA: per-block (1024 elems) sums
__global__ __launch_bounds__(256) void k2_scanA(
    const int* __restrict__ counts, int* __restrict__ bsum, int N)
{
    const int b = blockIdx.x, t = threadIdx.x;
    const int i0 = b * 1024 + t * 4;
    int s = 0;
    if (i0 + 3 < N) {
        int4 v = *(const int4*)(counts + i0);
        s = v.x + v.y + v.z + v.w;
    } else {
        for (int k = 0; k < 4; ++k) if (i0 + k < N) s += counts[i0 + k];
    }
    const int lane = t & 63, wid = t >> 6;
#pragma unroll
    for (int o = 1; o < 64; o <<= 1) s += __shfl_xor(s, o, 64);
    __shared__ int ws[4];
    if (lane == 0) ws[wid] = s;
    __syncthreads();
    if (t == 0) bsum[b] = ws[0] + ws[1] + ws[2] + ws[3];
}

// scanB: exclusive scan of block sums (1 block of 64); also writes offsets[N]
__global__ __launch_bounds__(64) void k2_scanB(
    const int* __restrict__ bsum, int* __restrict__ boff, int NB,
    int* __restrict__ offsets, int N)
{
    const int t = threadIdx.x;
    int carry = 0;
    for (int base = 0; base < NB; base += 64) {
        int v = (base + t < NB) ? bsum[base + t] : 0;
        int incl = v;
#pragma unroll
        for (int o = 1; o < 64; o <<= 1) {
            int u = __shfl_up(incl, o, 64);
            if (t >= o) incl += u;
        }
        if (base + t < NB) boff[base + t] = carry + incl - v;
        carry += __shfl(incl, 63, 64);
    }
    if (t == 0) offsets[N] = carry;
}

// scanC: per-block re-scan with block offset; writes offsets + cursor
__global__ __launch_bounds__(256) void k2_scanC(
    const int* __restrict__ counts, const int* __restrict__ boff,
    int* __restrict__ offsets, int* __restrict__ cursor, int N)
{
    const int b = blockIdx.x, t = threadIdx.x;
    const int i0 = b * 1024 + t * 4;
    int c0 = 0, c1 = 0, c2 = 0, c3 = 0;
    if (i0 + 3 < N) {
        int4 v = *(const int4*)(counts + i0);
        c0 = v.x; c1 = v.y; c2 = v.z; c3 = v.w;
    } else {
        if (i0     < N) c0 = counts[i0];
        if (i0 + 1 < N) c1 = counts[i0 + 1];
        if (i0 + 2 < N) c2 = counts[i0 + 2];
        if (i0 + 3 < N) c3 = counts[i0 + 3];
    }
    const int s4 = c0 + c1 + c2 + c3;
    const int lane = t & 63, wid = t >> 6;
    int incl = s4;
#pragma unroll
    for (int o = 1; o < 64; o <<= 1) {
        int u = __shfl_up(incl, o, 64);
        if (lane >= o) incl += u;
    }
    __shared__ int ws[4];
    if (lane == 63) ws[wid] = incl;
    __syncthreads();
    int woff = 0;
    for (int w = 0; w < wid; ++w) woff += ws[w];
    const int pref = boff[b] + woff + incl - s4;
    const int o0 = pref, o1 = pref + c0, o2 = o1 + c1, o3 = o2 + c2;
    if (i0 + 3 < N) {
        *(int4*)(offsets + i0) = make_int4(o0, o1, o2, o3);
        *(int4*)(cursor  + i0) = make_int4(o0, o1, o2, o3);
    } else {
        if (i0     < N) { offsets[i0]     = o0; cursor[i0]     = o0; }
        if (i0 + 1 < N) { offsets[i0 + 1] = o1; cursor[i0 + 1] = o1; }
        if (i0 + 2 < N) { offsets[i0 + 2] = o2; cursor[i0 + 2] = o2; }
        if (i0 + 3 < N) { offsets[i0 + 3] = o3; cursor[i0 + 3] = o3; }
    }
}

// ---------------- K2c: fill CSR ------------------------------------------
__global__ void k2_fill(const int* __restrict__ ei, int* __restrict__ cursor,
                        int* __restrict__ csr_src, int E, int N)
{
    int i = blockIdx.x * blockDim.x + threadIdx.x;
    int total = E + N;
    if (i < total) {
        int s, d;
        if (i < E) { s = ei[i]; d = ei[E + i]; }
        else       { s = d = i - E; }
        int pos = atomicAdd(&cursor[d], 1);
        csr_src[pos] = s;
    }
}

// ---------------- K3: per-dst softmax aggregation (no-max, bf16 gather) ----
// block = 256 = 4 waves; wave == head; lane == channel. Barrier-free.
__global__ __launch_bounds__(256) void k3_aggregate(
    const ushort_t* __restrict__ hb, const float* __restrict__ a_src,
    const float* __restrict__ a_dst, const int* __restrict__ offsets,
    const int* __restrict__ csr_src, const float* __restrict__ bias,
    ushort_t* __restrict__ act, int N)
{
    __shared__ float s_p[HEADSc][64];
    __shared__ int   s_src[HEADSc][64];

    const int n = blockIdx.x;
    const int head = threadIdx.x >> 6, lane = threadIdx.x & 63;
    const int beg = offsets[n], end = offsets[n + 1];
    const float adst = a_dst[n * HEADSc + head];

    float acc = 0.f, ssum = 0.f;

    for (int cb = beg; cb < end; cb += 64) {
        const int cnt = min(64, end - cb);
        const bool valid = lane < cnt;
        const int  sn = valid ? csr_src[cb + lane] : 0;
        float av = a_src[sn * HEADSc + head] + adst;
        av = (av > 0.f) ? av : 0.2f * av;                 // leaky_relu
        const float p = valid ? __expf(av) : 0.f;         // no max shift needed
        ssum += p;
        s_p[head][lane]   = p;
        s_src[head][lane] = sn;
        // same-wave LDS write->read: compiler-inserted lgkmcnt, no barrier

        float accc = 0.f;
#pragma unroll 4
        for (int e = 0; e < cnt; ++e) {
            const float pe = s_p[head][e];
            const int   sv = s_src[head][e];
            const ushort_t u = hb[(size_t)sv * HCc + head * HIDc + lane];
            accc += pe * bf2f(u);                          // 128B line per (edge,head)
        }
        acc += accc;
    }

#pragma unroll
    for (int o = 1; o < 64; o <<= 1) ssum += __shfl_xor(ssum, o, 64);

    float o = acc / (ssum + 1e-16f);
    o += bias[threadIdx.x];
    o = (o > 0.f) ? o : (__expf(o) - 1.f);                 // ELU
    act[(size_t)n * HCc + threadIdx.x] = f2bf(o);
}

// ---------------- K4: out = act(bf16) @ W_lin + b_lin ----------------------
// block = 256, 32 nodes/block; LDS holds fp32-converted act rows.
__global__ __launch_bounds__(256) void k4_gemm2(
    const ushort_t* __restrict__ act, const float* __restrict__ Wl,
    const float* __restrict__ bl, float* __restrict__ out, int N)
{
    __shared__ float as[32][HCc];           // 32 KB
    const int t = threadIdx.x;
    const int base = blockIdx.x * 32;
    for (int i = t * 4; i < 32 * HCc; i += 1024) {
        int n = i >> 8, k = i & 255;
        int gn = base + n;
        if (gn < N) {
            uint2 v = *(const uint2*)(act + (size_t)gn * HCc + k);
            as[n][k]     = __uint_as_float(v.x << 16);
            as[n][k + 1] = __uint_as_float(v.x & 0xFFFF0000u);
            as[n][k + 2] = __uint_as_float(v.y << 16);
            as[n][k + 3] = __uint_as_float(v.y & 0xFFFF0000u);
        } else {
            as[n][k] = as[n][k+1] = as[n][k+2] = as[n][k+3] = 0.f;
        }
    }
    __syncthreads();

    const int j = t & 63, ng = t >> 6;      // wave ng owns nodes ng*8..ng*8+7
    float acc[8] = {0.f};
    for (int k = 0; k < HCc; ++k) {
        float w = Wl[k * HIDc + j];         // Wl is 64KB total -> L2-resident
#pragma unroll
        for (int i = 0; i < 8; ++i) acc[i] += as[ng * 8 + i][k] * w;
    }
    float b = bl[j];
#pragma unroll
    for (int i = 0; i < 8; ++i) {
        int gn = base + ng * 8 + i;
        if (gn < N) out[(size_t)gn * HIDc + j] = acc[i] + b;
    }
}

// ---------------------------------------------------------------------------
extern "C" void kernel_launch(void* const* d_in, const int* in_sizes, int n_in,
                              void* d_out, int out_size, void* d_ws, size_t ws_size,
                              hipStream_t stream)
{
    const float* x       = (const float*)d_in[0];
    const int*   ei      = (const int*)  d_in[1];
    const float* Wg      = (const float*)d_in[2];
    const float* att_src = (const float*)d_in[3];
    const float* att_dst = (const float*)d_in[4];
    const float* bias_g  = (const float*)d_in[5];
    const float* Wl      = (const float*)d_in[6];
    const float* bl      = (const float*)d_in[7];
    float* out = (float*)d_out;

    const int N = in_sizes[0] / HIDc;       // 50000
    const int E = in_sizes[1] / 2;          // 800000
    const int total = E + N;
    const int NB = (N + 1023) / 1024;       // scan blocks (49)

    char* w = (char*)d_ws;
    size_t off = 0;
    auto carve = [&](size_t bytes) {
        void* p = w + off;
        off = (off + bytes + 255) & ~(size_t)255;
        return p;
    };
    ushort_t* h     = (ushort_t*)carve((size_t)N * HCc * 2);
    ushort_t* act   = (ushort_t*)carve((size_t)N * HCc * 2);
    float* a_src    = (float*)carve((size_t)N * HEADSc * 4);
    float* a_dst    = (float*)carve((size_t)N * HEADSc * 4);
    int*   counts   = (int*)  carve((size_t)N * 4);
    int*   offsets  = (int*)  carve((size_t)(N + 1) * 4);
    int*   cursor   = (int*)  carve((size_t)N * 4);
    int*   csr_src  = (int*)  carve((size_t)total * 4);
    int*   bsum     = (int*)  carve((size_t)NB * 4);
    int*   boff     = (int*)  carve((size_t)NB * 4);
    (void)ws_size;

    hipMemsetAsync(counts, 0, (size_t)N * 4, stream);

    k1_gemm1<<<(N + 31) / 32, 256, 0, stream>>>(x, Wg, att_src, att_dst,
                                                h, a_src, a_dst, N);
    k2_count<<<(total + 255) / 256, 256, 0, stream>>>(ei, counts, E, N);
    k2_scanA<<<NB, 256, 0, stream>>>(counts, bsum, N);
    k2_scanB<<<1, 64, 0, stream>>>(bsum, boff, NB, offsets, N);
    k2_scanC<<<NB, 256, 0, stream>>>(counts, boff, offsets, cursor, N);
    k2_fill<<<(total + 255) / 256, 256, 0, stream>>>(ei, cursor, csr_src, E, N);
    k3_aggregate<<<N, 256, 0, stream>>>(h, a_src, a_dst, offsets, csr_src,
                                        bias_g, act, N);
    k4_gemm2<<<(N + 31) / 32, 256, 0, stream>>>(act, Wl, bl, out, N);
}

// Round 4
// 364.681 us; speedup vs baseline: 1.5173x; 1.1044x over previous
//
#include <hip/hip_runtime.h>

#define HIDc 64
#define HEADSc 4
#define HCc 256   // HEADS*HID

typedef unsigned short ushort_t;
typedef unsigned int uint_t;

__device__ inline ushort_t f2bf(float f) {  // RNE
    uint_t u = __float_as_uint(f);
    u += 0x7FFFu + ((u >> 16) & 1u);
    return (ushort_t)(u >> 16);
}
__device__ inline float lrelu(float a) { return a > 0.f ? a : 0.2f * a; }
__device__ inline float elu(float o)  { return o > 0.f ? o : (__expf(o) - 1.f); }

// ---------------- K1: h = x @ W_gat  (+ a_src, a_dst); h stored bf16 -------
__global__ __launch_bounds__(256) void k1_gemm1(
    const float* __restrict__ x, const float* __restrict__ Wg,
    const float* __restrict__ att_src, const float* __restrict__ att_dst,
    ushort_t* __restrict__ h, float* __restrict__ a_src, float* __restrict__ a_dst,
    int N)
{
    __shared__ float xs[32][HIDc];          // 8 KB
    const int t = threadIdx.x;
    const int base = blockIdx.x * 32;
    for (int i = t; i < 32 * HIDc; i += 256) {
        int n = i >> 6, k = i & 63;
        int gn = base + n;
        xs[n][k] = (gn < N) ? x[(size_t)gn * HIDc + k] : 0.f;
    }
    __syncthreads();

    float acc[32];
#pragma unroll
    for (int n = 0; n < 32; ++n) acc[n] = 0.f;
    for (int k = 0; k < HIDc; ++k) {
        float w = Wg[k * HCc + t];          // Wg is 64KB total -> L2-resident
#pragma unroll
        for (int n = 0; n < 32; ++n) acc[n] += xs[n][k] * w;
    }

    const int head = t >> 6, c = t & 63;
    const float asv = att_src[t];
    const float adv = att_dst[t];

    for (int n = 0; n < 32; ++n) {
        int gn = base + n;
        if (gn < N) h[(size_t)gn * HCc + t] = f2bf(acc[n]);
    }
    for (int n = 0; n < 32; ++n) {
        float ps = acc[n] * asv;
        float pd = acc[n] * adv;
#pragma unroll
        for (int off = 32; off > 0; off >>= 1) {
            ps += __shfl_down(ps, off, 64);
            pd += __shfl_down(pd, off, 64);
        }
        if (c == 0) {
            int gn = base + n;
            if (gn < N) {
                a_src[gn * HEADSc + head] = ps;
                a_dst[gn * HEADSc + head] = pd;
            }
        }
    }
}

// ---------------- K2a: count in-degrees (incl. self-loops) ----------------
__global__ void k2_count(const int* __restrict__ ei, int* __restrict__ counts,
                         int E, int N)
{
    int i = blockIdx.x * blockDim.x + threadIdx.x;
    int total = E + N;
    if (i < total) {
        int d = (i < E) ? ei[E + i] : (i - E);
        atomicAdd(&counts[d], 1);
    }
}

// ---------------- K2b: parallel scan, 3 kernels ----------------------------
__global__ __launch_bounds__(256) void k2_scanA(
    const int* __restrict__ counts, int* __restrict__ bsum, int N)
{
    const int b = blockIdx.x, t = threadIdx.x;
    const int i0 = b * 1024 + t * 4;
    int s = 0;
    if (i0 + 3 < N) {
        int4 v = *(const int4*)(counts + i0);
        s = v.x + v.y + v.z + v.w;
    } else {
        for (int k = 0; k < 4; ++k) if (i0 + k < N) s += counts[i0 + k];
    }
    const int lane = t & 63, wid = t >> 6;
#pragma unroll
    for (int o = 1; o < 64; o <<= 1) s += __shfl_xor(s, o, 64);
    __shared__ int ws[4];
    if (lane == 0) ws[wid] = s;
    __syncthreads();
    if (t == 0) bsum[b] = ws[0] + ws[1] + ws[2] + ws[3];
}

__global__ __launch_bounds__(64) void k2_scanB(
    const int* __restrict__ bsum, int* __restrict__ boff, int NB,
    int* __restrict__ offsets, int N)
{
    const int t = threadIdx.x;
    int carry = 0;
    for (int base = 0; base < NB; base += 64) {
        int v = (base + t < NB) ? bsum[base + t] : 0;
        int incl = v;
#pragma unroll
        for (int o = 1; o < 64; o <<= 1) {
            int u = __shfl_up(incl, o, 64);
            if (t >= o) incl += u;
        }
        if (base + t < NB) boff[base + t] = carry + incl - v;
        carry += __shfl(incl, 63, 64);
    }
    if (t == 0) offsets[N] = carry;
}

__global__ __launch_bounds__(256) void k2_scanC(
    const int* __restrict__ counts, const int* __restrict__ boff,
    int* __restrict__ offsets, int* __restrict__ cursor, int N)
{
    const int b = blockIdx.x, t = threadIdx.x;
    const int i0 = b * 1024 + t * 4;
    int c0 = 0, c1 = 0, c2 = 0, c3 = 0;
    if (i0 + 3 < N) {
        int4 v = *(const int4*)(counts + i0);
        c0 = v.x; c1 = v.y; c2 = v.z; c3 = v.w;
    } else {
        if (i0     < N) c0 = counts[i0];
        if (i0 + 1 < N) c1 = counts[i0 + 1];
        if (i0 + 2 < N) c2 = counts[i0 + 2];
        if (i0 + 3 < N) c3 = counts[i0 + 3];
    }
    const int s4 = c0 + c1 + c2 + c3;
    const int lane = t & 63, wid = t >> 6;
    int incl = s4;
#pragma unroll
    for (int o = 1; o < 64; o <<= 1) {
        int u = __shfl_up(incl, o, 64);
        if (lane >= o) incl += u;
    }
    __shared__ int ws[4];
    if (lane == 63) ws[wid] = incl;
    __syncthreads();
    int woff = 0;
    for (int w = 0; w < wid; ++w) woff += ws[w];
    const int pref = boff[b] + woff + incl - s4;
    const int o0 = pref, o1 = pref + c0, o2 = o1 + c1, o3 = o2 + c2;
    if (i0 + 3 < N) {
        *(int4*)(offsets + i0) = make_int4(o0, o1, o2, o3);
        *(int4*)(cursor  + i0) = make_int4(o0, o1, o2, o3);
    } else {
        if (i0     < N) { offsets[i0]     = o0; cursor[i0]     = o0; }
        if (i0 + 1 < N) { offsets[i0 + 1] = o1; cursor[i0 + 1] = o1; }
        if (i0 + 2 < N) { offsets[i0 + 2] = o2; cursor[i0 + 2] = o2; }
        if (i0 + 3 < N) { offsets[i0 + 3] = o3; cursor[i0 + 3] = o3; }
    }
}

// ---------------- K2c: fill CSR ------------------------------------------
__global__ void k2_fill(const int* __restrict__ ei, int* __restrict__ cursor,
                        int* __restrict__ csr_src, int E, int N)
{
    int i = blockIdx.x * blockDim.x + threadIdx.x;
    int total = E + N;
    if (i < total) {
        int s, d;
        if (i < E) { s = ei[i]; d = ei[E + i]; }
        else       { s = d = i - E; }
        int pos = atomicAdd(&cursor[d], 1);
        csr_src[pos] = s;
    }
}

// ---------------- K3: one wave per node, all heads per lane ----------------
// block = 256 = 4 waves = 4 nodes. Barrier-free (wave-private LDS slabs).
// Lane layout: head = lane>>4, 4 channels = (lane&15)*4 .. +3 within head.
__global__ __launch_bounds__(256) void k3_aggregate(
    const uint2* __restrict__ h2,          // h rows: 64 x uint2 (512B) per node
    const float4* __restrict__ a_src4,     // [N] float4 (one per node, 4 heads)
    const float4* __restrict__ a_dst4,
    const int* __restrict__ offsets, const int* __restrict__ csr_src,
    const float4* __restrict__ bias4,      // 64 x float4
    uint2* __restrict__ act2, int N)
{
    __shared__ float s_p[HEADSc][64 * 4];  // [wave][edge*4 + head]   4 KB
    __shared__ int   s_src[HEADSc][64];    // [wave][edge]            1 KB

    const int wid = threadIdx.x >> 6, lane = threadIdx.x & 63;
    const int n = blockIdx.x * 4 + wid;
    if (n >= N) return;

    const int beg = offsets[n], end = offsets[n + 1];
    const float4 adst = a_dst4[n];
    const int head = lane >> 4, sub = lane & 15;
    const uint_t cix = (uint_t)(head * 16 + sub);   // uint2 index within row

    float acc0 = 0.f, acc1 = 0.f, acc2 = 0.f, acc3 = 0.f;
    float den = 0.f;

    float* pw = s_p[wid];
    int*   sw = s_src[wid];

    for (int cb = beg; cb < end; cb += 64) {
        const int cnt = min(64, end - cb);
        // ---- phase 1: lane == edge slot; p for all 4 heads, one f4 gather --
        const int sn = (lane < cnt) ? csr_src[cb + lane] : 0;
        const float4 as = a_src4[sn];
        float p0 = __expf(lrelu(as.x + adst.x));
        float p1 = __expf(lrelu(as.y + adst.y));
        float p2 = __expf(lrelu(as.z + adst.z));
        float p3 = __expf(lrelu(as.w + adst.w));
        ((float4*)pw)[lane] = make_float4(p0, p1, p2, p3);  // garbage slots never read
        sw[lane] = sn;
        // same-wave LDS RAW: compiler inserts lgkmcnt, no barrier needed

        // ---- phase 2: lane == (head, 4 channels); full row in one uint2 ----
#pragma unroll 4
        for (int e = 0; e < cnt; ++e) {
            const int   sv = sw[e];                  // broadcast
            const float pe = pw[e * 4 + head];       // 4 words, conflict-free
            den += pe;                               // exact per-head denom
            const uint2 v = h2[(uint_t)sv * 64u + cix];
            acc0 += pe * __uint_as_float(v.x << 16);
            acc1 += pe * __uint_as_float(v.x & 0xFFFF0000u);
            acc2 += pe * __uint_as_float(v.y << 16);
            acc3 += pe * __uint_as_float(v.y & 0xFFFF0000u);
        }
    }

    const float r = 1.f / (den + 1e-16f);
    const float4 b = bias4[cix];
    const float o0 = elu(acc0 * r + b.x);
    const float o1 = elu(acc1 * r + b.y);
    const float o2 = elu(acc2 * r + b.z);
    const float o3 = elu(acc3 * r + b.w);
    uint2 ov;
    ov.x = (uint_t)f2bf(o0) | ((uint_t)f2bf(o1) << 16);
    ov.y = (uint_t)f2bf(o2) | ((uint_t)f2bf(o3) << 16);
    act2[(uint_t)n * 64u + cix] = ov;
}

// ---------------- K4: out = act(bf16) @ W_lin + b_lin ----------------------
__global__ __launch_bounds__(256) void k4_gemm2(
    const ushort_t* __restrict__ act, const float* __restrict__ Wl,
    const float* __restrict__ bl, float* __restrict__ out, int N)
{
    __shared__ float as[32][HCc];           // 32 KB
    const int t = threadIdx.x;
    const int base = blockIdx.x * 32;
    for (int i = t * 4; i < 32 * HCc; i += 1024) {
        int n = i >> 8, k = i & 255;
        int gn = base + n;
        if (gn < N) {
            uint2 v = *(const uint2*)(act + (size_t)gn * HCc + k);
            as[n][k]     = __uint_as_float(v.x << 16);
            as[n][k + 1] = __uint_as_float(v.x & 0xFFFF0000u);
            as[n][k + 2] = __uint_as_float(v.y << 16);
            as[n][k + 3] = __uint_as_float(v.y & 0xFFFF0000u);
        } else {
            as[n][k] = as[n][k+1] = as[n][k+2] = as[n][k+3] = 0.f;
        }
    }
    __syncthreads();

    const int j = t & 63, ng = t >> 6;
    float acc[8] = {0.f};
    for (int k = 0; k < HCc; ++k) {
        float w = Wl[k * HIDc + j];
#pragma unroll
        for (int i = 0; i < 8; ++i) acc[i] += as[ng * 8 + i][k] * w;
    }
    float b = bl[j];
#pragma unroll
    for (int i = 0; i < 8; ++i) {
        int gn = base + ng * 8 + i;
        if (gn < N) out[(size_t)gn * HIDc + j] = acc[i] + b;
    }
}

// ---------------------------------------------------------------------------
extern "C" void kernel_launch(void* const* d_in, const int* in_sizes, int n_in,
                              void* d_out, int out_size, void* d_ws, size_t ws_size,
                              hipStream_t stream)
{
    const float* x       = (const float*)d_in[0];
    const int*   ei      = (const int*)  d_in[1];
    const float* Wg      = (const float*)d_in[2];
    const float* att_src = (const float*)d_in[3];
    const float* att_dst = (const float*)d_in[4];
    const float* bias_g  = (const float*)d_in[5];
    const float* Wl      = (const float*)d_in[6];
    const float* bl      = (const float*)d_in[7];
    float* out = (float*)d_out;

    const int N = in_sizes[0] / HIDc;       // 50000
    const int E = in_sizes[1] / 2;          // 800000
    const int total = E + N;
    const int NB = (N + 1023) / 1024;

    char* w = (char*)d_ws;
    size_t off = 0;
    auto carve = [&](size_t bytes) {
        void* p = w + off;
        off = (off + bytes + 255) & ~(size_t)255;
        return p;
    };
    ushort_t* h     = (ushort_t*)carve((size_t)N * HCc * 2);
    ushort_t* act   = (ushort_t*)carve((size_t)N * HCc * 2);
    float* a_src    = (float*)carve((size_t)N * HEADSc * 4);
    float* a_dst    = (float*)carve((size_t)N * HEADSc * 4);
    int*   counts   = (int*)  carve((size_t)N * 4);
    int*   offsets  = (int*)  carve((size_t)(N + 1) * 4);
    int*   cursor   = (int*)  carve((size_t)N * 4);
    int*   csr_src  = (int*)  carve((size_t)total * 4);
    int*   bsum     = (int*)  carve((size_t)NB * 4);
    int*   boff     = (int*)  carve((size_t)NB * 4);
    (void)ws_size;

    hipMemsetAsync(counts, 0, (size_t)N * 4, stream);

    k1_gemm1<<<(N + 31) / 32, 256, 0, stream>>>(x, Wg, att_src, att_dst,
                                                h, a_src, a_dst, N);
    k2_count<<<(total + 255) / 256, 256, 0, stream>>>(ei, counts, E, N);
    k2_scanA<<<NB, 256, 0, stream>>>(counts, bsum, N);
    k2_scanB<<<1, 64, 0, stream>>>(bsum, boff, NB, offsets, N);
    k2_scanC<<<NB, 256, 0, stream>>>(counts, boff, offsets, cursor, N);
    k2_fill<<<(total + 255) / 256, 256, 0, stream>>>(ei, cursor, csr_src, E, N);
    k3_aggregate<<<(N + 3) / 4, 256, 0, stream>>>(
        (const uint2*)h, (const float4*)a_src, (const float4*)a_dst,
        offsets, csr_src, (const float4*)bias_g, (uint2*)act, N);
    k4_gemm2<<<(N + 31) / 32, 256, 0, stream>>>(act, Wl, bl, out, N);
}

// Round 7
// 286.240 us; speedup vs baseline: 1.9331x; 1.2740x over previous
//
#include <hip/hip_runtime.h>

#define HIDc 64
#define HEADSc 4
#define HCc 256   // HEADS*HID

typedef unsigned short ushort_t;
typedef unsigned int uint_t;
typedef __attribute__((ext_vector_type(8))) short bf16x8;
typedef __attribute__((ext_vector_type(4))) float f32x4;

__device__ inline ushort_t f2bf(float f) {  // RNE
    uint_t u = __float_as_uint(f);
    u += 0x7FFFu + ((u >> 16) & 1u);
    return (ushort_t)(u >> 16);
}
__device__ inline float bfu(uint_t lo16) { return __uint_as_float(lo16 << 16); }
__device__ inline float lrelu(float a) { return a > 0.f ? a : 0.2f * a; }
__device__ inline float elu(float o)  { return o > 0.f ? o : (__expf(o) - 1.f); }

// ---------------- K0: weight prep: WgT bf16 [256][64], WlT bf16 [64][256] --
__global__ __launch_bounds__(256) void k0_prep(
    const float* __restrict__ Wg, const float* __restrict__ Wl,
    ushort_t* __restrict__ WgT, ushort_t* __restrict__ WlT)
{
    int i = blockIdx.x * 256 + threadIdx.x;
    if (i < 64 * 256) {                      // Wg [64][256] -> WgT [256][64]
        int k = i >> 8, n = i & 255;
        WgT[n * 64 + k] = f2bf(Wg[i]);
    } else {                                 // Wl [256][64] -> WlT [64][256]
        int j = i - 64 * 256;
        int k = j >> 6, n = j & 63;
        WlT[n * 256 + k] = f2bf(Wl[j]);
    }
}

// ---------------- K1: h = x @ W_gat via MFMA (bf16 in, bf16 out) ----------
// block = 4 waves; block owns 32 nodes x 256 cols; wave w owns cols 64w..64w+63.
__global__ __launch_bounds__(256) void k1_mfma(
    const float* __restrict__ x, const ushort_t* __restrict__ WgT,
    ushort_t* __restrict__ h, int N)
{
    const int w = threadIdx.x >> 6, l = threadIdx.x & 63;
    const int lr = l & 15, ko = l >> 4;
    const int base = blockIdx.x * 32;
    const int colb = w * 64;

    // A-frags: mt in {0,1} (16-row tiles), kb in {0,1} (K=32 halves)
    bf16x8 afr[2][2];
#pragma unroll
    for (int mt = 0; mt < 2; ++mt) {
        int row = base + mt * 16 + lr;
        int rowc = row < N ? row : N - 1;
        const float* xr = x + (size_t)rowc * HIDc + ko * 8;
#pragma unroll
        for (int kb = 0; kb < 2; ++kb) {
            float t0[8];
            *(float4*)t0       = *(const float4*)(xr + kb * 32);
            *(float4*)(t0 + 4) = *(const float4*)(xr + kb * 32 + 4);
            bf16x8 a;
#pragma unroll
            for (int j = 0; j < 8; ++j) a[j] = (short)f2bf(t0[j]);
            afr[mt][kb] = a;
        }
    }

    f32x4 acc[2][4];
#pragma unroll
    for (int mt = 0; mt < 2; ++mt)
#pragma unroll
        for (int nt = 0; nt < 4; ++nt) acc[mt][nt] = (f32x4)0.f;

#pragma unroll
    for (int nt = 0; nt < 4; ++nt) {
        const int col = colb + nt * 16 + lr;
        const ushort_t* wr = WgT + col * HIDc + ko * 8;
        bf16x8 b0 = *(const bf16x8*)wr;
        bf16x8 b1 = *(const bf16x8*)(wr + 32);
#pragma unroll
        for (int mt = 0; mt < 2; ++mt) {
            acc[mt][nt] = __builtin_amdgcn_mfma_f32_16x16x32_bf16(
                afr[mt][0], b0, acc[mt][nt], 0, 0, 0);
            acc[mt][nt] = __builtin_amdgcn_mfma_f32_16x16x32_bf16(
                afr[mt][1], b1, acc[mt][nt], 0, 0, 0);
        }
    }

    // C layout: col = lane&15, row = (lane>>4)*4 + r
#pragma unroll
    for (int mt = 0; mt < 2; ++mt)
#pragma unroll
        for (int r = 0; r < 4; ++r) {
            int row = base + mt * 16 + ko * 4 + r;
            if (row < N) {
#pragma unroll
                for (int nt = 0; nt < 4; ++nt)
                    h[(size_t)row * HCc + colb + nt * 16 + lr] =
                        f2bf(acc[mt][nt][r]);
            }
        }
}

// ---------------- K1b: a_src/a_dst from h (one wave per node) --------------
__global__ __launch_bounds__(256) void k1b_attn(
    const uint2* __restrict__ h2, const float4* __restrict__ as4,
    const float4* __restrict__ ad4, float* __restrict__ a_src,
    float* __restrict__ a_dst, int N)
{
    const int wid = threadIdx.x >> 6, l = threadIdx.x & 63;
    const int n = blockIdx.x * 4 + wid;
    if (n >= N) return;
    const uint2 v = h2[(size_t)n * 64 + l];
    const float4 a = as4[l];                 // att_src packed: f4 index == lane
    const float4 d = ad4[l];
    const float h0 = bfu(v.x & 0xFFFFu), h1 = bfu(v.x >> 16);
    const float h2v = bfu(v.y & 0xFFFFu), h3 = bfu(v.y >> 16);
    float ps = h0 * a.x + h1 * a.y + h2v * a.z + h3 * a.w;
    float pd = h0 * d.x + h1 * d.y + h2v * d.z + h3 * d.w;
#pragma unroll
    for (int o = 1; o < 16; o <<= 1) {       // reduce within 16-lane head group
        ps += __shfl_xor(ps, o, 64);
        pd += __shfl_xor(pd, o, 64);
    }
    if ((l & 15) == 0) {
        a_src[n * HEADSc + (l >> 4)] = ps;
        a_dst[n * HEADSc + (l >> 4)] = pd;
    }
}

// ---------------- K2a: count in-degrees (incl. self-loops) ----------------
__global__ void k2_count(const int* __restrict__ ei, int* __restrict__ counts,
                         int E, int N)
{
    int i = blockIdx.x * blockDim.x + threadIdx.x;
    int total = E + N;
    if (i < total) {
        int d = (i < E) ? ei[E + i] : (i - E);
        atomicAdd(&counts[d], 1);
    }
}

// ---------------- K2b: parallel scan, 3 kernels ----------------------------
__global__ __launch_bounds__(256) void k2_scanA(
    const int* __restrict__ counts, int* __restrict__ bsum, int N)
{
    const int b = blockIdx.x, t = threadIdx.x;
    const int i0 = b * 1024 + t * 4;
    int s = 0;
    if (i0 + 3 < N) {
        int4 v = *(const int4*)(counts + i0);
        s = v.x + v.y + v.z + v.w;
    } else {
        for (int k = 0; k < 4; ++k) if (i0 + k < N) s += counts[i0 + k];
    }
    const int lane = t & 63, wid = t >> 6;
#pragma unroll
    for (int o = 1; o < 64; o <<= 1) s += __shfl_xor(s, o, 64);
    __shared__ int ws[4];
    if (lane == 0) ws[wid] = s;
    __syncthreads();
    if (t == 0) bsum[b] = ws[0] + ws[1] + ws[2] + ws[3];
}

__global__ __launch_bounds__(64) void k2_scanB(
    const int* __restrict__ bsum, int* __restrict__ boff, int NB,
    int* __restrict__ offsets, int N)
{
    const int t = threadIdx.x;
    int carry = 0;
    for (int base = 0; base < NB; base += 64) {
        int v = (base + t < NB) ? bsum[base + t] : 0;
        int incl = v;
#pragma unroll
        for (int o = 1; o < 64; o <<= 1) {
            int u = __shfl_up(incl, o, 64);
            if (t >= o) incl += u;
        }
        if (base + t < NB) boff[base + t] = carry + incl - v;
        carry += __shfl(incl, 63, 64);
    }
    if (t == 0) offsets[N] = carry;
}

__global__ __launch_bounds__(256) void k2_scanC(
    const int* __restrict__ counts, const int* __restrict__ boff,
    int* __restrict__ offsets, int* __restrict__ cursor, int N)
{
    const int b = blockIdx.x, t = threadIdx.x;
    const int i0 = b * 1024 + t * 4;
    int c0 = 0, c1 = 0, c2 = 0, c3 = 0;
    if (i0 + 3 < N) {
        int4 v = *(const int4*)(counts + i0);
        c0 = v.x; c1 = v.y; c2 = v.z; c3 = v.w;
    } else {
        if (i0     < N) c0 = counts[i0];
        if (i0 + 1 < N) c1 = counts[i0 + 1];
        if (i0 + 2 < N) c2 = counts[i0 + 2];
        if (i0 + 3 < N) c3 = counts[i0 + 3];
    }
    const int s4 = c0 + c1 + c2 + c3;
    const int lane = t & 63, wid = t >> 6;
    int incl = s4;
#pragma unroll
    for (int o = 1; o < 64; o <<= 1) {
        int u = __shfl_up(incl, o, 64);
        if (lane >= o) incl += u;
    }
    __shared__ int ws[4];
    if (lane == 63) ws[wid] = incl;
    __syncthreads();
    int woff = 0;
    for (int w = 0; w < wid; ++w) woff += ws[w];
    const int pref = boff[b] + woff + incl - s4;
    const int o0 = pref, o1 = pref + c0, o2 = o1 + c1, o3 = o2 + c2;
    if (i0 + 3 < N) {
        *(int4*)(offsets + i0) = make_int4(o0, o1, o2, o3);
        *(int4*)(cursor  + i0) = make_int4(o0, o1, o2, o3);
    } else {
        if (i0     < N) { offsets[i0]     = o0; cursor[i0]     = o0; }
        if (i0 + 1 < N) { offsets[i0 + 1] = o1; cursor[i0 + 1] = o1; }
        if (i0 + 2 < N) { offsets[i0 + 2] = o2; cursor[i0 + 2] = o2; }
        if (i0 + 3 < N) { offsets[i0 + 3] = o3; cursor[i0 + 3] = o3; }
    }
}

// ---------------- K2c: fill CSR ------------------------------------------
__global__ void k2_fill(const int* __restrict__ ei, int* __restrict__ cursor,
                        int* __restrict__ csr_src, int E, int N)
{
    int i = blockIdx.x * blockDim.x + threadIdx.x;
    int total = E + N;
    if (i < total) {
        int s, d;
        if (i < E) { s = ei[i]; d = ei[E + i]; }
        else       { s = d = i - E; }
        int pos = atomicAdd(&cursor[d], 1);
        csr_src[pos] = s;
    }
}

// ---------------- K3: one wave per node, all heads per lane ----------------
__global__ __launch_bounds__(256) void k3_aggregate(
    const uint2* __restrict__ h2,
    const float4* __restrict__ a_src4,
    const float4* __restrict__ a_dst4,
    const int* __restrict__ offsets, const int* __restrict__ csr_src,
    const float4* __restrict__ bias4,
    uint2* __restrict__ act2, int N)
{
    __shared__ float s_p[HEADSc][64 * 4];
    __shared__ int   s_src[HEADSc][64];

    const int wid = threadIdx.x >> 6, lane = threadIdx.x & 63;
    const int n = blockIdx.x * 4 + wid;
    if (n >= N) return;

    const int beg = offsets[n], end = offsets[n + 1];
    const float4 adst = a_dst4[n];
    const int head = lane >> 4, sub = lane & 15;
    const uint_t cix = (uint_t)(head * 16 + sub);

    float acc0 = 0.f, acc1 = 0.f, acc2 = 0.f, acc3 = 0.f;
    float den = 0.f;

    float* pw = s_p[wid];
    int*   sw = s_src[wid];

    for (int cb = beg; cb < end; cb += 64) {
        const int cnt = min(64, end - cb);
        const int sn = (lane < cnt) ? csr_src[cb + lane] : 0;
        const float4 as = a_src4[sn];
        float p0 = __expf(lrelu(as.x + adst.x));
        float p1 = __expf(lrelu(as.y + adst.y));
        float p2 = __expf(lrelu(as.z + adst.z));
        float p3 = __expf(lrelu(as.w + adst.w));
        ((float4*)pw)[lane] = make_float4(p0, p1, p2, p3);
        sw[lane] = sn;

        float accc0 = 0.f, accc1 = 0.f, accc2 = 0.f, accc3 = 0.f;
#pragma unroll 4
        for (int e = 0; e < cnt; ++e) {
            const int   sv = sw[e];
            const float pe = pw[e * 4 + head];
            den += pe;
            const uint2 v = h2[(uint_t)sv * 64u + cix];
            accc0 += pe * __uint_as_float(v.x << 16);
            accc1 += pe * __uint_as_float(v.x & 0xFFFF0000u);
            accc2 += pe * __uint_as_float(v.y << 16);
            accc3 += pe * __uint_as_float(v.y & 0xFFFF0000u);
        }
        acc0 += accc0; acc1 += accc1; acc2 += accc2; acc3 += accc3;
    }

    const float r = 1.f / (den + 1e-16f);
    const float4 b = bias4[cix];
    const float o0 = elu(acc0 * r + b.x);
    const float o1 = elu(acc1 * r + b.y);
    const float o2 = elu(acc2 * r + b.z);
    const float o3 = elu(acc3 * r + b.w);
    uint2 ov;
    ov.x = (uint_t)f2bf(o0) | ((uint_t)f2bf(o1) << 16);
    ov.y = (uint_t)f2bf(o2) | ((uint_t)f2bf(o3) << 16);
    act2[(uint_t)n * 64u + cix] = ov;
}

// ---------------- K4: out = act @ W_lin + b_lin via MFMA -------------------
// block = 4 waves = 64 nodes; wave w owns rows base+16w..+15, all 64 cols.
__global__ __launch_bounds__(256) void k4_mfma(
    const ushort_t* __restrict__ act, const ushort_t* __restrict__ WlT,
    const float* __restrict__ bl, float* __restrict__ out, int N)
{
    const int w = threadIdx.x >> 6, l = threadIdx.x & 63;
    const int lr = l & 15, ko = l >> 4;
    const int base = blockIdx.x * 64 + w * 16;

    f32x4 acc[4];
#pragma unroll
    for (int nt = 0; nt < 4; ++nt) acc[nt] = (f32x4)0.f;

    int row = base + lr;
    int rowc = row < N ? row : N - 1;
    const ushort_t* ar = act + (size_t)rowc * HCc + ko * 8;

#pragma unroll
    for (int kb = 0; kb < 8; ++kb) {
        bf16x8 a = *(const bf16x8*)(ar + kb * 32);
#pragma unroll
        for (int nt = 0; nt < 4; ++nt) {
            const int col = nt * 16 + lr;
            bf16x8 b = *(const bf16x8*)(WlT + col * HCc + kb * 32 + ko * 8);
            acc[nt] = __builtin_amdgcn_mfma_f32_16x16x32_bf16(a, b, acc[nt], 0, 0, 0);
        }
    }

#pragma unroll
    for (int r = 0; r < 4; ++r) {
        int orow = base + ko * 4 + r;
        if (orow < N) {
#pragma unroll
            for (int nt = 0; nt < 4; ++nt)
                out[(size_t)orow * HIDc + nt * 16 + lr] = acc[nt][r] + bl[nt * 16 + lr];
        }
    }
}

// ---------------------------------------------------------------------------
extern "C" void kernel_launch(void* const* d_in, const int* in_sizes, int n_in,
                              void* d_out, int out_size, void* d_ws, size_t ws_size,
                              hipStream_t stream)
{
    const float* x       = (const float*)d_in[0];
    const int*   ei      = (const int*)  d_in[1];
    const float* Wg      = (const float*)d_in[2];
    const float* att_src = (const float*)d_in[3];
    const float* att_dst = (const float*)d_in[4];
    const float* bias_g  = (const float*)d_in[5];
    const float* Wl      = (const float*)d_in[6];
    const float* bl      = (const float*)d_in[7];
    float* out = (float*)d_out;

    const int N = in_sizes[0] / HIDc;       // 50000
    const int E = in_sizes[1] / 2;          // 800000
    const int total = E + N;
    const int NB = (N + 1023) / 1024;

    char* w = (char*)d_ws;
    size_t off = 0;
    auto carve = [&](size_t bytes) {
        void* p = w + off;
        off = (off + bytes + 255) & ~(size_t)255;
        return p;
    };
    ushort_t* h     = (ushort_t*)carve((size_t)N * HCc * 2);
    ushort_t* act   = (ushort_t*)carve((size_t)N * HCc * 2);
    float* a_src    = (float*)carve((size_t)N * HEADSc * 4);
    float* a_dst    = (float*)carve((size_t)N * HEADSc * 4);
    int*   counts   = (int*)  carve((size_t)N * 4);
    int*   offsets  = (int*)  carve((size_t)(N + 1) * 4);
    int*   cursor   = (int*)  carve((size_t)N * 4);
    int*   csr_src  = (int*)  carve((size_t)total * 4);
    int*   bsum     = (int*)  carve((size_t)NB * 4);
    int*   boff     = (int*)  carve((size_t)NB * 4);
    ushort_t* WgT   = (ushort_t*)carve((size_t)HIDc * HCc * 2);
    ushort_t* WlT   = (ushort_t*)carve((size_t)HCc * HIDc * 2);
    (void)ws_size;

    hipMemsetAsync(counts, 0, (size_t)N * 4, stream);

    k0_prep<<<128, 256, 0, stream>>>(Wg, Wl, WgT, WlT);
    k1_mfma<<<(N + 31) / 32, 256, 0, stream>>>(x, WgT, h, N);
    k1b_attn<<<(N + 3) / 4, 256, 0, stream>>>(
        (const uint2*)h, (const float4*)att_src, (const float4*)att_dst,
        a_src, a_dst, N);
    k2_count<<<(total + 255) / 256, 256, 0, stream>>>(ei, counts, E, N);
    k2_scanA<<<NB, 256, 0, stream>>>(counts, bsum, N);
    k2_scanB<<<1, 64, 0, stream>>>(bsum, boff, NB, offsets, N);
    k2_scanC<<<NB, 256, 0, stream>>>(counts, boff, offsets, cursor, N);
    k2_fill<<<(total + 255) / 256, 256, 0, stream>>>(ei, cursor, csr_src, E, N);
    k3_aggregate<<<(N + 3) / 4, 256, 0, stream>>>(
        (const uint2*)h, (const float4*)a_src, (const float4*)a_dst,
        offsets, csr_src, (const float4*)bias_g, (uint2*)act, N);
    k4_mfma<<<(N + 63) / 64, 256, 0, stream>>>(act, WlT, bl, out, N);
}